// Round 6
// baseline (220.237 us; speedup 1.0000x reference)
//
#include <hip/hip_runtime.h>

// De-emphasis IIR: y[n] = x[n] + C*y[n-1] per row, 64 rows of 480000 fp32.
//
// R10 (post-mortem of R4-R9): six structures all pinned at ~2.5 TB/s.
// Smoking gun is VGPR_Count: R6=20, R8=36, R9=32 -- R9's declared PF=8
// float4 ring alone needs 32 data VGPRs, so the compiler provably SANK the
// ring loads to just before each use (conditional refill + modular ring made
// that profitable), collapsing effective MLP to ~1KB/wave in EVERY round.
// Per-wave throughput = outstanding/latency ~ 0.5-1 GB/s -> aggregate
// ~2.5 TB/s invariant to occupancy/structure/shuffles -- exactly observed.
//
// R10 makes MLP structurally impossible to collapse:
//   - BATCH LOAD: all 17 passes (68 VGPRs, 17 KB/wave) loaded in straight-
//     line unconditional code, then asm memory barrier, then compute. The
//     68 destination registers are live across the barrier -> vmcnt=17
//     guaranteed. 16 waves/CU x 17 KB x 256 CU ~ 70 MB chip-wide in flight
//     >> ~6 MB BDP -> memory system becomes the limiter, not latency.
//   - wave scan VECTORIZED ACROSS PASSES: 6 shfl steps x 17 independent
//     shfls (DS latency paid 6x/wave) vs 17 chains x 8 dependent shfls.
//   - unconditional loads via clamp-low addressing (only widx==0 halo lanes
//     clamp; their contribution is zeroed by one wave-uniform select);
//     unconditional stores by exact fill (125*3840=480000).
//   - B63 via v_readlane -> SGPR (no extra DS op); 17x2 fma carry chain.
//
// Cross-wave carry: 512-elem halo (2 passes); 0.97^512 ~ 1.7e-7 (validated
// R1-R9: absmax 0.0625 = fp32 association noise, threshold 0.4475).

#define COEFF 0.97f
#define ROW_LEN 480000
#define SPAN_W 256                          // elems per wave-pass (64 x 4)
#define HALO 512
#define P_HALO 2
#define P_OUT 15
#define P_TOT (P_OUT + P_HALO)              // 17
#define OUT_W (P_OUT * SPAN_W)              // 3840; 125*3840 = 480000 exact
#define WPR (ROW_LEN / OUT_W)               // 125 waves per row
#define BLOCK 256
#define WAVES (BLOCK / 64)                  // 4 independent waves per block

typedef float v4f __attribute__((ext_vector_type(4)));

constexpr float fpow(float b, int n) {
    float r = 1.0f;
    for (int i = 0; i < n; ++i) r *= b;
    return r;
}
// wave-scan step factors: C^(4 * 2^k)
constexpr float S0 = fpow(COEFF, 4);
constexpr float S1 = fpow(COEFF, 8);
constexpr float S2 = fpow(COEFF, 16);
constexpr float S3 = fpow(COEFF, 32);
constexpr float S4 = fpow(COEFF, 64);
constexpr float S5 = fpow(COEFF, 128);
constexpr float CP = fpow(COEFF, SPAN_W);   // C^256 per-pass carry decay
constexpr float C1P = fpow(COEFF, 1);
constexpr float C2P = fpow(COEFF, 2);
constexpr float C3P = fpow(COEFF, 3);
constexpr float C4P = fpow(COEFF, 4);

__device__ __forceinline__ float bcast63(float v) {
    return __int_as_float(__builtin_amdgcn_readlane(__float_as_int(v), 63));
}

template <int D>
__device__ __forceinline__ void scan_step(float (&Bv)[P_TOT], float F, int lane) {
    float Bp[P_TOT];
    #pragma unroll
    for (int t = 0; t < P_TOT; ++t) Bp[t] = __shfl_up(Bv[t], D);
    #pragma unroll
    for (int t = 0; t < P_TOT; ++t)
        if (lane >= D) Bv[t] = fmaf(F, Bp[t], Bv[t]);
}

__global__ __launch_bounds__(BLOCK, 4) void deemph_kernel(const float* __restrict__ x,
                                                          float* __restrict__ y,
                                                          int n_rows) {
    const int lane = threadIdx.x & 63;
    const int wave = threadIdx.x >> 6;
    const int gw   = blockIdx.x * WAVES + wave;   // global wave id
    const int row  = gw / WPR;                    // const-div -> magic mul
    const int widx = gw - row * WPR;
    if (row >= n_rows) return;                    // wave-uniform

    const float* __restrict__ xrow = x + (long long)row * ROW_LEN;
    float* __restrict__ yrow       = y + (long long)row * ROW_LEN;

    // lane's element base for pass 0 (passes 0,1 = halo; <0 only at widx 0)
    const int lbase = widx * OUT_W - HALO + 4 * lane;

    // Aex = C^(4*lane): exact bit-product, loop-invariant
    float Aex = 1.0f;
    if (lane & 1)  Aex *= S0;
    if (lane & 2)  Aex *= S1;
    if (lane & 4)  Aex *= S2;
    if (lane & 8)  Aex *= S3;
    if (lane & 16) Aex *= S4;
    if (lane & 32) Aex *= S5;

    // ---- Phase 1: batch-load ALL 17 passes (68 VGPRs), unconditional ----
    v4f rb[P_TOT];
    #pragma unroll
    for (int t = 0; t < P_TOT; ++t) {
        int e = lbase + t * SPAN_W;
        e = e < 0 ? 0 : e;     // only widx==0 halo lanes clamp (values unused)
        rb[t] = *(const v4f*)(xrow + e);
    }
    // Pin all loads above this point: 68 dest regs live across the barrier,
    // sinking impossible, vmcnt ramps to 17.
    asm volatile("" ::: "memory");

    // ---- Phase 2: local 4-elem scans, in place (independent across t) ----
    #pragma unroll
    for (int t = 0; t < P_TOT; ++t) {
        rb[t].y = fmaf(COEFF, rb[t].x, rb[t].y);
        rb[t].z = fmaf(COEFF, rb[t].y, rb[t].z);
        rb[t].w = fmaf(COEFF, rb[t].z, rb[t].w);
    }

    // ---- Phase 3: wave scans, vectorized across passes (6 steps) ----
    float Bv[P_TOT];
    #pragma unroll
    for (int t = 0; t < P_TOT; ++t) Bv[t] = rb[t].w;
    scan_step<1>(Bv, S0, lane);
    scan_step<2>(Bv, S1, lane);
    scan_step<4>(Bv, S2, lane);
    scan_step<8>(Bv, S3, lane);
    scan_step<16>(Bv, S4, lane);
    scan_step<32>(Bv, S5, lane);

    // exclusive prefix per pass; wave totals to SGPRs via readlane
    float Bex[P_TOT];
    #pragma unroll
    for (int t = 0; t < P_TOT; ++t) {
        Bex[t] = __shfl_up(Bv[t], 1);
        if (lane == 0) Bex[t] = 0.0f;
    }
    float B63[P_TOT];
    #pragma unroll
    for (int t = 0; t < P_TOT; ++t) B63[t] = bcast63(Bv[t]);

    // ---- Phase 4: carry chain + fused output stores ----
    float c = 0.0f;
    #pragma unroll
    for (int t = 0; t < P_TOT; ++t) {
        if (t == P_HALO) c = (widx == 0) ? 0.0f : c;  // row start: carry = 0
        const float Kt = fmaf(c, Aex, Bex[t]);  // y just before lane's seg
        c = fmaf(c, CP, B63[t]);                // 2-fma/pass scalar-fed chain
        if (t >= P_HALO) {
            const int e = lbase + t * SPAN_W;   // in [0, ROW_LEN) by exact fill
            v4f o;
            o.x = fmaf(Kt, C1P, rb[t].x);
            o.y = fmaf(Kt, C2P, rb[t].y);
            o.z = fmaf(Kt, C3P, rb[t].z);
            o.w = fmaf(Kt, C4P, rb[t].w);
            *(v4f*)(yrow + e) = o;
        }
    }
}

extern "C" void kernel_launch(void* const* d_in, const int* in_sizes, int n_in,
                              void* d_out, int out_size, void* d_ws, size_t ws_size,
                              hipStream_t stream) {
    (void)n_in; (void)d_ws; (void)ws_size; (void)out_size;
    const float* x = (const float*)d_in[0];
    float* y = (float*)d_out;
    const int n_rows = in_sizes[0] / ROW_LEN;           // 64 for (32,2,480000)
    const int nblocks = (WPR * n_rows + WAVES - 1) / WAVES;  // 2000 exact
    deemph_kernel<<<dim3(nblocks), BLOCK, 0, stream>>>(x, y, n_rows);
}

// Round 7
// 218.957 us; speedup vs baseline: 1.0058x; 1.0058x over previous
//
#include <hip/hip_runtime.h>

// De-emphasis IIR: y[n] = x[n] + C*y[n-1] per row, 64 rows of 480000 fp32.
//
// R11 (post-mortem of R4-R10): every attempt to hold in-flight data in VGPRs
// fails -- the compiler either SINKS the prefetch (R6/R9: VGPR=20-32, ring
// provably not live) or SPILLS it (R10: VGPR=64 of 68 needed, WRITE_SIZE
// 120->140 MB = scratch traffic). Aggregate stuck at ~2.5 TB/s; R10's
// partial MLP gain pushed HBM to 2.72 TB/s (best yet) -> MLP theory holds,
// register file is just the wrong buffer.
//
// R11 buffers in the HARDWARE queue + LDS instead, where the compiler can't
// undo it: global_load_lds DMA (zero VGPRs, tracked only by in-order vmcnt)
// into a PER-WAVE private 6-slot x 1KB LDS ring. No barriers anywhere: the
// only consumer of a wave's slots is the wave itself, ordered by its own
// vmcnt (in-order retirement, m135). Per pass:
//   s_waitcnt vmcnt(W_p)   ; W_p = exact count of VMEM ops newer than this
//                          ; pass's DMA: {5,5,5,6,7,8,9,10,11,11,11,11,
//                          ; 10,9,8,7,6} -- computed constexpr per unrolled
//                          ; iteration, loads NEVER drained to 0
//   ds_read_b128 own 16B   -> lgkmcnt(0) -> refill DMA into freed slot
//   3-fma local scan; 6-shfl wave scan (A lane-constant); Bex via algebra
//   (Bv - l3) * C^-4 (saves the 7th shuffle); B63 via readlane (VALU);
//   2-fma carry chain; coalesced v4f store.
// 6 KB/wave guaranteed outstanding; 24 KB LDS/block -> 6 blocks/CU ->
// 24 waves/CU; VGPR ~40.
//
// Cross-wave carry: 512-elem halo (2 passes); 0.97^512 ~ 1.7e-7 (validated
// R1-R10: absmax 0.0625 = fp32 association noise, threshold 0.4475).
// Exact fill: 125 waves/row x 3840 out-elems = 480000; all predicates
// wave-uniform; only widx==0's halo clamps (contribution zeroed via carry
// reset at t==P_HALO).

#define COEFF 0.97f
#define ROW_LEN 480000
#define SPAN_W 256                          // elems per wave-pass (64 x 4)
#define HALO 512
#define P_HALO 2
#define P_OUT 15
#define P_TOT (P_OUT + P_HALO)              // 17
#define OUT_W (P_OUT * SPAN_W)              // 3840; 125*3840 = 480000 exact
#define WPR (ROW_LEN / OUT_W)               // 125 waves per row
#define BLOCK 256
#define WAVES (BLOCK / 64)
#define RING 6                              // LDS ring slots (1 KB each)

typedef float v4f __attribute__((ext_vector_type(4)));

constexpr float fpow(float b, int n) {
    float r = 1.0f;
    for (int i = 0; i < n; ++i) r *= b;
    return r;
}
// wave-scan step factors: C^(4 * 2^k)
constexpr float S0 = fpow(COEFF, 4);
constexpr float S1 = fpow(COEFF, 8);
constexpr float S2 = fpow(COEFF, 16);
constexpr float S3 = fpow(COEFF, 32);
constexpr float S4 = fpow(COEFF, 64);
constexpr float S5 = fpow(COEFF, 128);
constexpr float CP  = fpow(COEFF, SPAN_W);  // C^256 per-pass carry decay
constexpr float C1P = fpow(COEFF, 1);
constexpr float C2P = fpow(COEFF, 2);
constexpr float C3P = fpow(COEFF, 3);
constexpr float C4P = fpow(COEFF, 4);
constexpr float IC4 = 1.0f / fpow(COEFF, 4); // C^-4 (exclusive-prefix algebra)

// Exact vmcnt wait for pass P's DMA, from in-order op accounting.
// Issue order: prologue D0..D5; iter k: [wait][ds_read][lgkm]
// [D_{k+RING} if k+RING<P_TOT][S_k if k>=P_HALO].
// Ops newer than D_P at iter P's wait:
//   DMAs  D_j, j in (P, min(P_TOT-1, P+RING-1)]
//   Stores S_k, k in [max(P_HALO, P-RING), P-1]   (S_{P-RING} issues AFTER
//                                                  D_P within iter P-RING)
constexpr int wcnt(int P) {
    const int hi  = (P + RING - 1 < P_TOT - 1) ? P + RING - 1 : P_TOT - 1;
    const int dma = hi - P;
    const int lo  = (P - RING > P_HALO) ? P - RING : P_HALO;
    int st = P - lo;
    if (st < 0) st = 0;
    return dma + st;
}

__device__ __forceinline__ float bcast63(float v) {
    return __int_as_float(__builtin_amdgcn_readlane(__float_as_int(v), 63));
}

__device__ __forceinline__ void issue_dma(const float* src, v4f* slot) {
    __builtin_amdgcn_global_load_lds(
        (const __attribute__((address_space(1))) void*)src,
        (__attribute__((address_space(3))) void*)slot, 16, 0, 0);
    // HW: LDS dest = wave-uniform slot base + lane*16; global src per-lane.
}

struct WaveCtx {
    const float* xrow;
    float* yrow;
    int   base0;        // widx*OUT_W - HALO (wave-uniform)
    int   lane;
    float Aex;          // C^(4*lane)
    bool  row_start;    // widx == 0
};

template <int P>
__device__ __forceinline__ void run_pass(const WaveCtx& cx, v4f (*slots)[64],
                                         float& c) {
    if constexpr (P < P_TOT) {
        // Wait for THIS pass's DMA only; keeps newer DMAs/stores in flight.
        asm volatile("s_waitcnt vmcnt(%0)" :: "i"(wcnt(P)) : "memory");

        v4f v = slots[P % RING][cx.lane];          // ds_read_b128
        // Slot data must be in regs before the refill DMA may overwrite it.
        asm volatile("s_waitcnt lgkmcnt(0)" ::: "memory");

        if constexpr (P + RING < P_TOT) {
            const int be = cx.base0 + (P + RING) * SPAN_W;  // >= 0 always
            issue_dma(cx.xrow + be + 4 * cx.lane, &slots[P % RING][0]);
        }

        // local inclusive scan (zero carry-in; carry folded at the end)
        const float l0 = v.x;
        const float l1 = fmaf(COEFF, l0, v.y);
        const float l2 = fmaf(COEFF, l1, v.z);
        const float l3 = fmaf(COEFF, l2, v.w);

        // wave inclusive scan on segment sums (A lane-constant per step)
        float Bv = l3, Bp;
        Bp = __shfl_up(Bv, 1);  if (cx.lane >= 1)  Bv = fmaf(S0, Bp, Bv);
        Bp = __shfl_up(Bv, 2);  if (cx.lane >= 2)  Bv = fmaf(S1, Bp, Bv);
        Bp = __shfl_up(Bv, 4);  if (cx.lane >= 4)  Bv = fmaf(S2, Bp, Bv);
        Bp = __shfl_up(Bv, 8);  if (cx.lane >= 8)  Bv = fmaf(S3, Bp, Bv);
        Bp = __shfl_up(Bv, 16); if (cx.lane >= 16) Bv = fmaf(S4, Bp, Bv);
        Bp = __shfl_up(Bv, 32); if (cx.lane >= 32) Bv = fmaf(S5, Bp, Bv);

        // exclusive prefix by algebra (lane 0: Bv==l3 bit-exact -> 0)
        const float Bex = (Bv - l3) * IC4;
        const float B63 = bcast63(Bv);             // VALU broadcast, no DS op

        float cc = c;
        if constexpr (P == P_HALO) { if (cx.row_start) cc = 0.0f; }
        const float Kt = fmaf(cc, cx.Aex, Bex);    // y just before lane's seg
        c = fmaf(cc, CP, B63);                     // 2-fma/pass carry chain

        if constexpr (P >= P_HALO) {
            const int e = cx.base0 + P * SPAN_W + 4 * cx.lane; // in-range
            v4f o;
            o.x = fmaf(Kt, C1P, l0);
            o.y = fmaf(Kt, C2P, l1);
            o.z = fmaf(Kt, C3P, l2);
            o.w = fmaf(Kt, C4P, l3);
            *(v4f*)(cx.yrow + e) = o;
        }

        run_pass<P + 1>(cx, slots, c);
    }
}

__global__ __launch_bounds__(BLOCK, 6) void deemph_kernel(const float* __restrict__ x,
                                                          float* __restrict__ y,
                                                          int n_rows) {
    __shared__ v4f lds[WAVES][RING][64];           // 24 KiB; per-wave private
    const int lane = threadIdx.x & 63;
    const int wave = threadIdx.x >> 6;
    const int gw   = blockIdx.x * WAVES + wave;
    const int row  = gw / WPR;                     // const-div -> magic mul
    const int widx = gw - row * WPR;
    if (row >= n_rows) return;                     // never taken (exact grid)

    WaveCtx cx;
    cx.xrow  = x + (long long)row * ROW_LEN;
    cx.yrow  = y + (long long)row * ROW_LEN;
    cx.base0 = widx * OUT_W - HALO;
    cx.lane  = lane;
    cx.row_start = (widx == 0);

    // Aex = C^(4*lane): exact bit-product, loop-invariant
    float Aex = 1.0f;
    if (lane & 1)  Aex *= S0;
    if (lane & 2)  Aex *= S1;
    if (lane & 4)  Aex *= S2;
    if (lane & 8)  Aex *= S3;
    if (lane & 16) Aex *= S4;
    if (lane & 32) Aex *= S5;
    cx.Aex = Aex;

    // prologue: fill the ring (6 DMAs in flight, 0 VGPRs consumed)
    #pragma unroll
    for (int q = 0; q < RING; ++q) {
        int be = cx.base0 + q * SPAN_W;
        be = be < 0 ? 0 : be;      // widx==0 halo clamp (contribution zeroed)
        issue_dma(cx.xrow + be + 4 * lane, &lds[wave][q][0]);
    }

    float c = 0.0f;
    run_pass<0>(cx, lds[wave], c);
}

extern "C" void kernel_launch(void* const* d_in, const int* in_sizes, int n_in,
                              void* d_out, int out_size, void* d_ws, size_t ws_size,
                              hipStream_t stream) {
    (void)n_in; (void)d_ws; (void)ws_size; (void)out_size;
    const float* x = (const float*)d_in[0];
    float* y = (float*)d_out;
    const int n_rows = in_sizes[0] / ROW_LEN;            // 64 for (32,2,480000)
    const int nblocks = (WPR * n_rows + WAVES - 1) / WAVES;  // 2000 exact
    deemph_kernel<<<dim3(nblocks), BLOCK, 0, stream>>>(x, y, n_rows);
}

// Round 8
// 215.006 us; speedup vs baseline: 1.0243x; 1.0184x over previous
//
#include <hip/hip_runtime.h>

// De-emphasis IIR: y[n] = x[n] + C*y[n-1] per row, 64 rows of 480000 fp32.
//
// R12 (post-mortem of R4-R11): R11 had a VERIFIED deep pipeline (VGPR=40,
// no spills, 6KB/wave held in the HW queue by counted vmcnt) and still sat
// at 2.47 TB/s. Conclusion: long-lived waves marching serially through
// passes cap at ~2.5 TB/s no matter how they're fed. The one kernel shape
// known to stream read+write at 6.3 TB/s on this chip (float4 copy) differs
// in two ways: work items are SHORT-LIVED (MLP replenished by wave
// replacement, not software pipelining) and every load is 16B/lane
// contiguous (also explains R7/R8's regression: SEG=16 loads were 64B-
// strided = 64 partial lines per instruction).
//
// R12 = the copy kernel's shape + scan compute:
//   - each row split into 375 INDEPENDENT items: 1280 out + 512 halo
//     = 7 passes of 256 elems (SEG=4/lane, perfectly coalesced).
//   - one wave per item: batch-issue all 7 loads (28 data VGPRs -- live
//     without spilling, unlike R10's 68), compiler barrier, vectorized
//     wave-scan (6 shfl steps x 7 independent shfls), 7-step carry chain
//     (2 fma each), 5 coalesced stores, wave DIES.
//   - 24,000 independent waves (~94/CU replacement depth), no LDS, no
//     barriers, no serial pass chain longer than 7.
//   - Bex via algebra (Bv - l3)*C^-4 (bit-exact 0 at lane 0, validated
//     R11); B63 via readlane (SGPR, no DS op).
// Read amp 7/5 = 1.4x at L1; ~1x at DRAM (L3 absorbs halo re-reads).
//
// Cross-item carry: 512-elem halo (2 passes); 0.97^512 ~ 1.7e-7 (validated
// R1-R11: absmax 0.0625 = fp32 association noise, threshold 0.4475).
// Exact fill: 375 * 1280 = 480000; stores unconditional and in-range;
// only widx==0's halo loads clamp (contribution zeroed by carry reset).

#define COEFF 0.97f
#define ROW_LEN 480000
#define SPAN_W 256                          // elems per pass (64 lanes x 4)
#define P_HALO 2
#define P_OUT 5
#define P_TOT (P_OUT + P_HALO)              // 7
#define OUT_W (P_OUT * SPAN_W)              // 1280; 375*1280 = 480000 exact
#define WPR (ROW_LEN / OUT_W)               // 375 items per row
#define BLOCK 256
#define WAVES (BLOCK / 64)                  // 4 independent waves per block

typedef float v4f __attribute__((ext_vector_type(4)));

constexpr float fpow(float b, int n) {
    float r = 1.0f;
    for (int i = 0; i < n; ++i) r *= b;
    return r;
}
// wave-scan step factors: C^(4 * 2^k)
constexpr float S0 = fpow(COEFF, 4);
constexpr float S1 = fpow(COEFF, 8);
constexpr float S2 = fpow(COEFF, 16);
constexpr float S3 = fpow(COEFF, 32);
constexpr float S4 = fpow(COEFF, 64);
constexpr float S5 = fpow(COEFF, 128);
constexpr float CP  = fpow(COEFF, SPAN_W);  // C^256 per-pass carry decay
constexpr float C1P = fpow(COEFF, 1);
constexpr float C2P = fpow(COEFF, 2);
constexpr float C3P = fpow(COEFF, 3);
constexpr float C4P = fpow(COEFF, 4);
constexpr float IC4 = 1.0f / fpow(COEFF, 4); // C^-4 exclusive-prefix algebra

__device__ __forceinline__ float bcast63(float v) {
    return __int_as_float(__builtin_amdgcn_readlane(__float_as_int(v), 63));
}

template <int D>
__device__ __forceinline__ void scan_step(float (&Bv)[P_TOT], float F, int lane) {
    float Bp[P_TOT];
    #pragma unroll
    for (int t = 0; t < P_TOT; ++t) Bp[t] = __shfl_up(Bv[t], D);
    #pragma unroll
    for (int t = 0; t < P_TOT; ++t)
        if (lane >= D) Bv[t] = fmaf(F, Bp[t], Bv[t]);
}

__global__ __launch_bounds__(BLOCK, 8) void deemph_kernel(const float* __restrict__ x,
                                                          float* __restrict__ y,
                                                          int n_rows) {
    const int lane = threadIdx.x & 63;
    const int wave = threadIdx.x >> 6;
    const int gw   = blockIdx.x * WAVES + wave;   // global item id
    const int row  = gw / WPR;                    // const-div -> magic mul
    const int widx = gw - row * WPR;
    if (row >= n_rows) return;                    // wave-uniform (exact grid)

    const float* __restrict__ xrow = x + (long long)row * ROW_LEN;
    float* __restrict__ yrow       = y + (long long)row * ROW_LEN;

    // element base of pass 0 for this lane (passes 0,1 = halo; <0 only widx 0)
    const int lbase = widx * OUT_W - P_HALO * SPAN_W + 4 * lane;

    // Aex = C^(4*lane): exact bit-product, uniform cost
    float Aex = 1.0f;
    if (lane & 1)  Aex *= S0;
    if (lane & 2)  Aex *= S1;
    if (lane & 4)  Aex *= S2;
    if (lane & 8)  Aex *= S3;
    if (lane & 16) Aex *= S4;
    if (lane & 32) Aex *= S5;

    // ---- batch-issue ALL 7 loads (28 data VGPRs, no spill risk) ----
    v4f rb[P_TOT];
    #pragma unroll
    for (int t = 0; t < P_TOT; ++t) {
        int e = lbase + t * SPAN_W;
        e = e < 0 ? 0 : e;     // only widx==0 halo lanes (values unused)
        rb[t] = *(const v4f*)(xrow + e);
    }
    // Pin all loads above: 28 dest regs live across the barrier, vmcnt -> 7.
    asm volatile("" ::: "memory");

    // ---- local 4-elem scans in place (independent across passes) ----
    #pragma unroll
    for (int t = 0; t < P_TOT; ++t) {
        rb[t].y = fmaf(COEFF, rb[t].x, rb[t].y);
        rb[t].z = fmaf(COEFF, rb[t].y, rb[t].z);
        rb[t].w = fmaf(COEFF, rb[t].z, rb[t].w);
    }

    // ---- wave scans vectorized across passes (6 shfl steps total) ----
    float Bv[P_TOT];
    #pragma unroll
    for (int t = 0; t < P_TOT; ++t) Bv[t] = rb[t].w;
    scan_step<1>(Bv, S0, lane);
    scan_step<2>(Bv, S1, lane);
    scan_step<4>(Bv, S2, lane);
    scan_step<8>(Bv, S3, lane);
    scan_step<16>(Bv, S4, lane);
    scan_step<32>(Bv, S5, lane);

    float B63[P_TOT];
    #pragma unroll
    for (int t = 0; t < P_TOT; ++t) B63[t] = bcast63(Bv[t]);  // SGPRs

    // ---- short carry chain + fused stores (wave then dies) ----
    float c = 0.0f;
    #pragma unroll
    for (int t = 0; t < P_TOT; ++t) {
        // exclusive prefix: (inclusive - own l3) / C^4; lane0 bit-exact 0
        const float Bex = (Bv[t] - rb[t].w) * IC4;
        float cc = c;
        if (t == P_HALO) cc = (widx == 0) ? 0.0f : cc;  // row start: carry 0
        const float Kt = fmaf(cc, Aex, Bex);   // y just before lane's segment
        c = fmaf(cc, CP, B63[t]);              // 2-fma/pass, 7-deep chain
        if (t >= P_HALO) {
            const int e = lbase + t * SPAN_W;  // in [0, ROW_LEN) by exact fill
            v4f o;
            o.x = fmaf(Kt, C1P, rb[t].x);
            o.y = fmaf(Kt, C2P, rb[t].y);
            o.z = fmaf(Kt, C3P, rb[t].z);
            o.w = fmaf(Kt, C4P, rb[t].w);
            *(v4f*)(yrow + e) = o;
        }
    }
}

extern "C" void kernel_launch(void* const* d_in, const int* in_sizes, int n_in,
                              void* d_out, int out_size, void* d_ws, size_t ws_size,
                              hipStream_t stream) {
    (void)n_in; (void)d_ws; (void)ws_size; (void)out_size;
    const float* x = (const float*)d_in[0];
    float* y = (float*)d_out;
    const int n_rows = in_sizes[0] / ROW_LEN;            // 64 for (32,2,480000)
    const int nblocks = (WPR * n_rows + WAVES - 1) / WAVES;  // 6000 exact
    deemph_kernel<<<dim3(nblocks), BLOCK, 0, stream>>>(x, y, n_rows);
}

// Round 9
// 209.252 us; speedup vs baseline: 1.0525x; 1.0275x over previous
//
#include <hip/hip_runtime.h>

// De-emphasis IIR: y[n] = x[n] + C*y[n-1] per row, 64 rows of 480000 fp32.
//
// R13 (post-mortem of R4-R12): the MLP/latency family is DEAD. R12's VGPR=28
// proves the register "batch" was interleaved away (28 regs can't hold 7
// live float4s + scan state; the asm memory clobber pins loads, not the
// dependent arithmetic the compiler hoisted up between them). The decisive
// datum is R11: hardware-VERIFIED 6 KB/wave in the DMA queue, ~36 MB chip-
// wide in flight (6x BDP), still 2.47 TB/s -> supply-capped, latency
// inflates to match (~14 us loaded). Eight structures, three load paths
// (L1/VGPR, LDS-DMA, batched), both store policies: all 2.4-2.7 TB/s.
//
// Last untested supply-side mechanism: L3 at-capacity churn. x+y = 246 MB
// sits exactly at the 256 MB Infinity Cache: every access allocates+evicts
// +writes-back with ~0 useful retention (FETCH=66MB of 123 shows partial x
// residency only). The harness's write-only fill (streaming path) hits
// 6.6 TB/s. R13 streams BOTH sides non-temporally (nt loads never tried;
// R9 tested nt stores alone = null):
//   - R12's independent-item structure (best: 73.6 us), widened to
//     P_OUT=15 so nt halo read-amp is only 17/15 = 1.13x.
//   - one wave = one item: 17 passes of 256 elems (SEG=4, 16B/lane
//     perfectly coalesced), simple per-pass loop (MLP proven irrelevant,
//     let the scheduler do what it wants), wave dies after 15 stores.
//   - per pass: 3-fma local scan, 6-shfl lane-constant wave scan,
//     Bex via algebra (Bv-l3)*C^-4 (bit-exact 0 at lane 0, validated
//     R11/R12), B63 via readlane, 2-fma carry chain.
//   - 8000 waves/row-set (125/row x 64), 2000 blocks, no LDS, no barriers.
//
// Cross-item carry: 512-elem halo (2 passes); 0.97^512 ~ 1.7e-7 (validated
// R1-R12: absmax 0.0625 = fp32 association noise, threshold 0.4475).
// Exact fill: 125 * 3840 = 480000; stores unconditional in-range; only
// widx==0's halo loads clamp (contribution zeroed by carry reset at p==2).

#define COEFF 0.97f
#define ROW_LEN 480000
#define SPAN_W 256                          // elems per pass (64 lanes x 4)
#define HALO 512
#define P_HALO 2
#define P_OUT 15
#define P_TOT (P_OUT + P_HALO)              // 17
#define OUT_W (P_OUT * SPAN_W)              // 3840; 125*3840 = 480000 exact
#define WPR (ROW_LEN / OUT_W)               // 125 items per row
#define BLOCK 256
#define WAVES (BLOCK / 64)                  // 4 independent waves per block

typedef float v4f __attribute__((ext_vector_type(4)));

constexpr float fpow(float b, int n) {
    float r = 1.0f;
    for (int i = 0; i < n; ++i) r *= b;
    return r;
}
// wave-scan step factors: C^(4 * 2^k)
constexpr float S0 = fpow(COEFF, 4);
constexpr float S1 = fpow(COEFF, 8);
constexpr float S2 = fpow(COEFF, 16);
constexpr float S3 = fpow(COEFF, 32);
constexpr float S4 = fpow(COEFF, 64);
constexpr float S5 = fpow(COEFF, 128);
constexpr float CP  = fpow(COEFF, SPAN_W);  // C^256 per-pass carry decay
constexpr float C1P = fpow(COEFF, 1);
constexpr float C2P = fpow(COEFF, 2);
constexpr float C3P = fpow(COEFF, 3);
constexpr float C4P = fpow(COEFF, 4);
constexpr float IC4 = 1.0f / fpow(COEFF, 4); // C^-4 exclusive-prefix algebra

__device__ __forceinline__ float bcast63(float v) {
    return __int_as_float(__builtin_amdgcn_readlane(__float_as_int(v), 63));
}

__global__ __launch_bounds__(BLOCK, 8) void deemph_kernel(const float* __restrict__ x,
                                                          float* __restrict__ y,
                                                          int n_rows) {
    const int lane = threadIdx.x & 63;
    const int wave = threadIdx.x >> 6;
    const int gw   = blockIdx.x * WAVES + wave;   // global item id
    const int row  = gw / WPR;                    // const-div -> magic mul
    const int widx = gw - row * WPR;
    if (row >= n_rows) return;                    // wave-uniform (exact grid)

    const float* __restrict__ xrow = x + (long long)row * ROW_LEN;
    float* __restrict__ yrow       = y + (long long)row * ROW_LEN;

    // element base of pass 0 for this lane (passes 0,1 = halo; <0 only widx 0)
    const int lbase = widx * OUT_W - HALO + 4 * lane;
    const bool row_start = (widx == 0);

    // Aex = C^(4*lane): exact bit-product, loop-invariant
    float Aex = 1.0f;
    if (lane & 1)  Aex *= S0;
    if (lane & 2)  Aex *= S1;
    if (lane & 4)  Aex *= S2;
    if (lane & 8)  Aex *= S3;
    if (lane & 16) Aex *= S4;
    if (lane & 32) Aex *= S5;

    float c = 0.0f;   // carry: y just before the current pass
    #pragma unroll
    for (int p = 0; p < P_TOT; ++p) {
        int e = lbase + p * SPAN_W;
        const int ec = e < 0 ? 0 : e;   // widx==0 halo clamp (values unused)
        // Non-temporal: stream x past the caches (no L3 allocate/evict churn)
        const v4f v = __builtin_nontemporal_load((const v4f*)(xrow + ec));

        // local inclusive scan (zero carry-in; carry folded at the end)
        const float l0 = v.x;
        const float l1 = fmaf(COEFF, l0, v.y);
        const float l2 = fmaf(COEFF, l1, v.z);
        const float l3 = fmaf(COEFF, l2, v.w);

        // wave inclusive scan on segment sums (A lane-constant per step)
        float Bv = l3, Bp;
        Bp = __shfl_up(Bv, 1);  if (lane >= 1)  Bv = fmaf(S0, Bp, Bv);
        Bp = __shfl_up(Bv, 2);  if (lane >= 2)  Bv = fmaf(S1, Bp, Bv);
        Bp = __shfl_up(Bv, 4);  if (lane >= 4)  Bv = fmaf(S2, Bp, Bv);
        Bp = __shfl_up(Bv, 8);  if (lane >= 8)  Bv = fmaf(S3, Bp, Bv);
        Bp = __shfl_up(Bv, 16); if (lane >= 16) Bv = fmaf(S4, Bp, Bv);
        Bp = __shfl_up(Bv, 32); if (lane >= 32) Bv = fmaf(S5, Bp, Bv);

        // exclusive prefix by algebra (lane 0: Bv==l3 bit-exact -> 0)
        const float Bex = (Bv - l3) * IC4;
        const float B63 = bcast63(Bv);            // VALU broadcast, no DS op

        float cc = c;
        if (p == P_HALO && row_start) cc = 0.0f;  // row start: carry = 0
        const float Kt = fmaf(cc, Aex, Bex);      // y just before lane's seg
        c = fmaf(cc, CP, B63);                    // 2-fma/pass carry chain

        if (p >= P_HALO) {
            // e in [0, ROW_LEN) by exact fill; stream y past the caches
            v4f o;
            o.x = fmaf(Kt, C1P, l0);
            o.y = fmaf(Kt, C2P, l1);
            o.z = fmaf(Kt, C3P, l2);
            o.w = fmaf(Kt, C4P, l3);
            __builtin_nontemporal_store(o, (v4f*)(yrow + e));
        }
    }
}

extern "C" void kernel_launch(void* const* d_in, const int* in_sizes, int n_in,
                              void* d_out, int out_size, void* d_ws, size_t ws_size,
                              hipStream_t stream) {
    (void)n_in; (void)d_ws; (void)ws_size; (void)out_size;
    const float* x = (const float*)d_in[0];
    float* y = (float*)d_out;
    const int n_rows = in_sizes[0] / ROW_LEN;            // 64 for (32,2,480000)
    const int nblocks = (WPR * n_rows + WAVES - 1) / WAVES;  // 2000 exact
    deemph_kernel<<<dim3(nblocks), BLOCK, 0, stream>>>(x, y, n_rows);
}

// Round 12
// 207.778 us; speedup vs baseline: 1.0600x; 1.0071x over previous
//
#include <hip/hip_runtime.h>

// De-emphasis IIR: y[n] = x[n] + C*y[n-1] per row, 64 rows of 480000 fp32.
//
// R15 = R14 re-expressed defensively after two container failures on the
// identical R14 source (R13's source ran fine; suspicion split between
// broker flakiness and a source-triggered harness issue). Changes are
// harness-facing only: launch signature reverted to R13's exact (x, y,
// n_rows) shape; n_items/n_half derived in-kernel; unconditional B-chain
// (n_items = 375*n_rows always even). Hypothesis and numerics unchanged.
//
// R14 theory (post-mortem of R4-R13): nt-both-sides (R13) gave the first
// real win (~71 us; nt LOAD active, R9's nt-store-alone null; harness's
// 491 MB poison-fill flushes L3 so streaming is optimal). Remaining gap to
// copy (3.4 vs 6.3 TB/s) after verified-dead MLP (R11), occupancy,
// shuffle intensity, fetch volume, store policy: ONE serial dependency
// chain per wave (load -> 3 fma -> 6 DEPENDENT shfls -> carry -> store).
// R10, the only >2.7 TB/s round, had max independent in-flight work.
// Fix: TWO independent chains per wave, ops written pairwise so even an
// in-order schedule alternates chains (2x issue ILP + load lookahead):
//   - 24000 independent items (7 passes of 256 elems, SEG=4, 16B/lane
//     coalesced); wave g processes items g and g+12000 (different rows).
//   - 12000 waves = 3000 blocks -> ~12 blocks/CU dispatched, 8 resident.
//     No LDS, no barriers.
//   - per chain per pass: 3-fma local scan, 6-shfl lane-constant wave
//     scan, Bex via algebra (Bv-l3)*C^-4 (bit-exact 0 at lane 0,
//     validated R11-R13), B63 via readlane, 2-fma carry chain, nt store.
//
// Cross-item carry: 512-elem halo (2 passes); 0.97^512 ~ 1.7e-7 (validated
// R1-R13: absmax 0.0625 = fp32 association noise, threshold 0.4475).
// Exact fill: 375 items/row x 1280 out = 480000; stores unconditional
// in-range; only widx==0 halo loads clamp (contribution zeroed by carry
// reset at p==P_HALO).

#define COEFF 0.97f
#define ROW_LEN 480000
#define SPAN_W 256                          // elems per pass (64 lanes x 4)
#define HALO 512
#define P_HALO 2
#define P_OUT 5
#define P_TOT (P_OUT + P_HALO)              // 7
#define OUT_W (P_OUT * SPAN_W)              // 1280; 375*1280 = 480000 exact
#define WPR (ROW_LEN / OUT_W)               // 375 items per row
#define BLOCK 256
#define WAVES (BLOCK / 64)                  // 4 independent waves per block

typedef float v4f __attribute__((ext_vector_type(4)));

constexpr float fpow(float b, int n) {
    float r = 1.0f;
    for (int i = 0; i < n; ++i) r *= b;
    return r;
}
// wave-scan step factors: C^(4 * 2^k)
constexpr float S0 = fpow(COEFF, 4);
constexpr float S1 = fpow(COEFF, 8);
constexpr float S2 = fpow(COEFF, 16);
constexpr float S3 = fpow(COEFF, 32);
constexpr float S4 = fpow(COEFF, 64);
constexpr float S5 = fpow(COEFF, 128);
constexpr float CP  = fpow(COEFF, SPAN_W);  // C^256 per-pass carry decay
constexpr float C1P = fpow(COEFF, 1);
constexpr float C2P = fpow(COEFF, 2);
constexpr float C3P = fpow(COEFF, 3);
constexpr float C4P = fpow(COEFF, 4);
constexpr float IC4 = 1.0f / fpow(COEFF, 4); // C^-4 exclusive-prefix algebra

__device__ __forceinline__ float bcast63(float v) {
    return __int_as_float(__builtin_amdgcn_readlane(__float_as_int(v), 63));
}

__global__ __launch_bounds__(BLOCK, 8) void deemph_kernel(const float* __restrict__ x,
                                                          float* __restrict__ y,
                                                          int n_rows) {
    const int lane = threadIdx.x & 63;
    const int wave = threadIdx.x >> 6;
    const int gw   = blockIdx.x * WAVES + wave;
    const int n_half = (WPR * n_rows) >> 1;       // 12000; n_items always even
    if (gw >= n_half) return;                     // wave-uniform (exact grid)

    const int iA = gw;
    const int iB = gw + n_half;                   // always < n_items

    const int rowA = iA / WPR, widxA = iA - rowA * WPR;   // magic-mul div
    const int rowB = iB / WPR, widxB = iB - rowB * WPR;

    const float* __restrict__ xrowA = x + (long long)rowA * ROW_LEN;
    float* __restrict__ yrowA       = y + (long long)rowA * ROW_LEN;
    const float* __restrict__ xrowB = x + (long long)rowB * ROW_LEN;
    float* __restrict__ yrowB       = y + (long long)rowB * ROW_LEN;

    // element base of pass 0 per chain (passes 0,1 = halo; <0 only widx==0)
    const int lbA = widxA * OUT_W - HALO + 4 * lane;
    const int lbB = widxB * OUT_W - HALO + 4 * lane;
    const bool rsA = (widxA == 0);
    const bool rsB = (widxB == 0);

    // Aex = C^(4*lane): exact bit-product, shared by both chains
    float Aex = 1.0f;
    if (lane & 1)  Aex *= S0;
    if (lane & 2)  Aex *= S1;
    if (lane & 4)  Aex *= S2;
    if (lane & 8)  Aex *= S3;
    if (lane & 16) Aex *= S4;
    if (lane & 32) Aex *= S5;

    float cA = 0.0f, cB = 0.0f;   // independent carry chains
    #pragma unroll
    for (int p = 0; p < P_TOT; ++p) {
        const int eA = lbA + p * SPAN_W;
        const int eB = lbB + p * SPAN_W;
        const int ecA = eA < 0 ? 0 : eA;          // halo clamp (values unused)
        const int ecB = eB < 0 ? 0 : eB;
        // nt loads: stream past the caches (poison-fill makes L3 useless)
        const v4f vA = __builtin_nontemporal_load((const v4f*)(xrowA + ecA));
        const v4f vB = __builtin_nontemporal_load((const v4f*)(xrowB + ecB));

        // local inclusive scans (independent)
        const float a0 = vA.x;
        const float b0 = vB.x;
        const float a1 = fmaf(COEFF, a0, vA.y);
        const float b1 = fmaf(COEFF, b0, vB.y);
        const float a2 = fmaf(COEFF, a1, vA.z);
        const float b2 = fmaf(COEFF, b1, vB.z);
        const float a3 = fmaf(COEFF, a2, vA.w);
        const float b3 = fmaf(COEFF, b2, vB.w);

        // dual wave scans, steps interleaved (independent DS chains)
        float BA = a3, BB = b3, pA, pB;
        pA = __shfl_up(BA, 1);  pB = __shfl_up(BB, 1);
        if (lane >= 1)  { BA = fmaf(S0, pA, BA); BB = fmaf(S0, pB, BB); }
        pA = __shfl_up(BA, 2);  pB = __shfl_up(BB, 2);
        if (lane >= 2)  { BA = fmaf(S1, pA, BA); BB = fmaf(S1, pB, BB); }
        pA = __shfl_up(BA, 4);  pB = __shfl_up(BB, 4);
        if (lane >= 4)  { BA = fmaf(S2, pA, BA); BB = fmaf(S2, pB, BB); }
        pA = __shfl_up(BA, 8);  pB = __shfl_up(BB, 8);
        if (lane >= 8)  { BA = fmaf(S3, pA, BA); BB = fmaf(S3, pB, BB); }
        pA = __shfl_up(BA, 16); pB = __shfl_up(BB, 16);
        if (lane >= 16) { BA = fmaf(S4, pA, BA); BB = fmaf(S4, pB, BB); }
        pA = __shfl_up(BA, 32); pB = __shfl_up(BB, 32);
        if (lane >= 32) { BA = fmaf(S5, pA, BA); BB = fmaf(S5, pB, BB); }

        // exclusive prefix by algebra (lane 0 bit-exact 0); totals via VALU
        const float BexA = (BA - a3) * IC4;
        const float BexB = (BB - b3) * IC4;
        const float B63A = bcast63(BA);
        const float B63B = bcast63(BB);

        float ccA = cA, ccB = cB;
        if (p == P_HALO) {                         // row start: carry = 0
            if (rsA) ccA = 0.0f;
            if (rsB) ccB = 0.0f;
        }
        const float KtA = fmaf(ccA, Aex, BexA);
        const float KtB = fmaf(ccB, Aex, BexB);
        cA = fmaf(ccA, CP, B63A);                  // 2-fma/pass carry chains
        cB = fmaf(ccB, CP, B63B);

        if (p >= P_HALO) {
            v4f oA, oB;
            oA.x = fmaf(KtA, C1P, a0);  oB.x = fmaf(KtB, C1P, b0);
            oA.y = fmaf(KtA, C2P, a1);  oB.y = fmaf(KtB, C2P, b1);
            oA.z = fmaf(KtA, C3P, a2);  oB.z = fmaf(KtB, C3P, b2);
            oA.w = fmaf(KtA, C4P, a3);  oB.w = fmaf(KtB, C4P, b3);
            __builtin_nontemporal_store(oA, (v4f*)(yrowA + eA));
            __builtin_nontemporal_store(oB, (v4f*)(yrowB + eB));
        }
    }
}

extern "C" void kernel_launch(void* const* d_in, const int* in_sizes, int n_in,
                              void* d_out, int out_size, void* d_ws, size_t ws_size,
                              hipStream_t stream) {
    (void)n_in; (void)d_ws; (void)ws_size; (void)out_size;
    const float* x = (const float*)d_in[0];
    float* y = (float*)d_out;
    const int n_rows  = in_sizes[0] / ROW_LEN;         // 64 for (32,2,480000)
    const int n_half  = (WPR * n_rows) / 2;            // 12000
    const int nblocks = (n_half + WAVES - 1) / WAVES;  // 3000 exact
    deemph_kernel<<<dim3(nblocks), BLOCK, 0, stream>>>(x, y, n_rows);
}